// Round 12
// baseline (117.411 us; speedup 1.0000x reference)
//
#include <hip/hip_runtime.h>

// DescriptorMatcher match_snn — R3 (resubmit; broker timeout, never ran): occupancy + B-prefetch.
// bf16 MFMA GEMM fused with branchless packed-int top-2 (proven R2, absmax 0.0):
//   A pre-scaled by -2, acc init = n2+COFF  =>  acc exits K-loop = m' > 0
//   packed u = (bits(m') & 0xFFFFE000) | col ; top-2 via u32 min/max, index embedded.
// R3 deltas: NCHUNK 16->32 (1024 blocks, 4/CU) ; double-buffered bfrag prefetch.

typedef __bf16 bf16x8 __attribute__((ext_vector_type(8)));
typedef __bf16 bf16x2 __attribute__((ext_vector_type(2)));
typedef float f32x4 __attribute__((ext_vector_type(4)));

#define NB 8192
#define DK 128
#define NCHUNK 32
#define CHUNK (NB / NCHUNK)   /* 256 cols per chunk */
#define JT (CHUNK / 16)       /* 16 col-tiles per chunk */
#define ROWS_PER_WAVE 64      /* 4 row-tiles of 16 */
#define BM 256                /* 4 waves per block */
#define COFF 512.0f           /* positivity offset for packed ordering */
#define VMASK 0xFFFFE000u     /* keep sign+exp+10 mantissa bits; low 13 = col */

// --- fused convert: desc1 -> -2*bf16, n1 raw ; desc2 -> bf16, n2+COFF ------
__global__ __launch_bounds__(256) void conv_norm_kernel(const float* __restrict__ desc1,
                                                        const float* __restrict__ desc2,
                                                        __bf16* __restrict__ d1b,
                                                        __bf16* __restrict__ d2b,
                                                        float* __restrict__ n1,
                                                        float* __restrict__ n2pc) {
    const int idx  = blockIdx.x * 4 + (threadIdx.x >> 6); // one wave per row
    const int lane = threadIdx.x & 63;
    const bool is2 = idx >= NB;
    const int row  = is2 ? idx - NB : idx;
    const float* src = is2 ? desc2 : desc1;
    const size_t off = (size_t)row * DK + lane * 2;
    const float2 v = *reinterpret_cast<const float2*>(src + off);
    float s = v.x * v.x + v.y * v.y;
    const float sc = is2 ? 1.0f : -2.0f;
    bf16x2 bp;
    bp[0] = (__bf16)(v.x * sc);
    bp[1] = (__bf16)(v.y * sc);
    *reinterpret_cast<bf16x2*>((is2 ? d2b : d1b) + off) = bp;
#pragma unroll
    for (int d = 1; d < 64; d <<= 1) s += __shfl_xor(s, d);
    if (lane == 0) {
        if (is2) n2pc[row] = s + COFF;
        else     n1[row] = s;
    }
}

// --- main: wave owns 64 rows x 256-col chunk; fused GEMM + packed top-2 ----
__global__ __launch_bounds__(256) void snn_main_kernel(const __bf16* __restrict__ d1b,
                                                       const __bf16* __restrict__ d2b,
                                                       const float* __restrict__ n2pc,
                                                       unsigned* __restrict__ pmin1,
                                                       unsigned* __restrict__ pmin2) {
    const int lane    = threadIdx.x & 63;
    const int wid     = threadIdx.x >> 6;
    const int rowbase = blockIdx.x * BM + wid * ROWS_PER_WAVE;
    const int colbase = blockIdx.y * CHUNK;
    const int lrow    = lane & 15;
    const int lk      = (lane >> 4) * 8;

    // A fragments (row = lane&15, k = (lane>>4)*8 + b) — A is pre-scaled by -2
    bf16x8 afrag[4][4];
#pragma unroll
    for (int rt = 0; rt < 4; ++rt)
#pragma unroll
        for (int kk = 0; kk < 4; ++kk)
            afrag[rt][kk] = *reinterpret_cast<const bf16x8*>(
                d1b + (size_t)(rowbase + rt * 16 + lrow) * DK + kk * 32 + lk);

    unsigned p1[16], p2[16];
#pragma unroll
    for (int s = 0; s < 16; ++s) { p1[s] = 0xFFFFFFFFu; p2[s] = 0xFFFFFFFFu; }

    const __bf16* bbase = d2b + (size_t)(colbase + lrow) * DK + lk;
    const float* n2p = n2pc + colbase + lrow;
    const unsigned colv = colbase + lrow;

    bf16x8 bufA[4], bufB[4];
#pragma unroll
    for (int kk = 0; kk < 4; ++kk)
        bufA[kk] = *reinterpret_cast<const bf16x8*>(bbase + kk * 32);

    // one jt step: MFMA on fragments in buf, fused packed top-2 update
    auto compute = [&](const bf16x8* buf, int jt) {
        const float n2c = n2p[jt * 16];      // per-lane col constant (col = lane&15)
        const unsigned col = colv + jt * 16;
#pragma unroll
        for (int rt = 0; rt < 4; ++rt) {
            f32x4 acc = {n2c, n2c, n2c, n2c}; // acc exits loop = n2 + C - 2*dot
#pragma unroll
            for (int kk = 0; kk < 4; ++kk)
                acc = __builtin_amdgcn_mfma_f32_16x16x32_bf16(afrag[rt][kk], buf[kk], acc, 0, 0, 0);
            // C/D layout: col = lane&15, row = (lane>>4)*4 + e
#pragma unroll
            for (int e = 0; e < 4; ++e) {
                const unsigned u = (__builtin_bit_cast(unsigned, acc[e]) & VMASK) | col;
                const int s = rt * 4 + e;
                const unsigned t = max(p1[s], u);
                p1[s] = min(p1[s], u);
                p2[s] = min(p2[s], t);
            }
        }
    };

    // double-buffered: prefetch jt+1 while computing jt (static buffer names)
    for (int jt = 0; jt < JT; jt += 2) {
        const __bf16* bpn = bbase + (size_t)(jt + 1) * 16 * DK;
#pragma unroll
        for (int kk = 0; kk < 4; ++kk)
            bufB[kk] = *reinterpret_cast<const bf16x8*>(bpn + kk * 32);
        compute(bufA, jt);
        if (jt + 2 < JT) {
            const __bf16* bpn2 = bbase + (size_t)(jt + 2) * 16 * DK;
#pragma unroll
            for (int kk = 0; kk < 4; ++kk)
                bufA[kk] = *reinterpret_cast<const bf16x8*>(bpn2 + kk * 32);
        }
        compute(bufB, jt + 1);
    }

    // cross-lane top-2 merge within each 16-lane group (same rows, diff cols)
#pragma unroll
    for (int s = 0; s < 16; ++s) {
        unsigned a1 = p1[s], a2 = p2[s];
#pragma unroll
        for (int d = 1; d <= 8; d <<= 1) {
            const unsigned o1 = __shfl_xor(a1, d);
            const unsigned o2 = __shfl_xor(a2, d);
            const unsigned t = max(a1, o1);
            a1 = min(a1, o1);
            a2 = min(min(a2, o2), t);
        }
        if (lrow == 0) {
            const int row = rowbase + (s >> 2) * 16 + (lane >> 4) * 4 + (s & 3);
            const size_t off = (size_t)blockIdx.y * NB + row;
            pmin1[off] = a1;
            pmin2[off] = a2;
        }
    }
}

// --- phase 2: merge chunk partials (packed), ratio test, write outputs -----
__global__ __launch_bounds__(256) void snn_reduce_kernel(const unsigned* __restrict__ pmin1,
                                                         const unsigned* __restrict__ pmin2,
                                                         const float* __restrict__ n1,
                                                         float* __restrict__ out) {
    const int i = blockIdx.x * 256 + threadIdx.x;
    unsigned a1 = 0xFFFFFFFFu, a2 = 0xFFFFFFFFu;
#pragma unroll
    for (int c = 0; c < NCHUNK; ++c) {
        const unsigned c1 = pmin1[(size_t)c * NB + i];
        const unsigned c2 = pmin2[(size_t)c * NB + i];
        const unsigned t = max(a1, c1);
        a1 = min(a1, c1);
        a2 = min(min(a2, c2), t);
    }
    const float v1 = __builtin_bit_cast(float, a1 & VMASK) - COFF; // n2 - 2*dot
    const float v2 = __builtin_bit_cast(float, a2 & VMASK) - COFF;
    const int idx = (int)(a1 & 0x1FFFu);
    const float nn = n1[i];
    const float d1 = sqrtf(fmaxf(nn + v1, 0.f));
    const float d2 = sqrtf(fmaxf(nn + v2, 0.f));
    const float ratio = d1 / d2;
    const bool mask = (ratio <= 0.8f); // NaN -> false, matches jnp
    out[i] = mask ? ratio : 0.0f;                      // match_dists (8192,1)
    out[NB + 2 * i] = mask ? (float)i : -1.0f;         // matches_idxs[:,0]
    out[NB + 2 * i + 1] = mask ? (float)idx : -1.0f;   // matches_idxs[:,1]
    out[3 * NB + i] = mask ? 1.0f : 0.0f;              // mask
}

extern "C" void kernel_launch(void* const* d_in, const int* in_sizes, int n_in,
                              void* d_out, int out_size, void* d_ws, size_t ws_size,
                              hipStream_t stream) {
    const float* desc1 = (const float*)d_in[0];
    const float* desc2 = (const float*)d_in[1];
    float* out = (float*)d_out;
    char* ws = (char*)d_ws;

    __bf16* d1b = (__bf16*)ws;                                   // 2 MB
    __bf16* d2b = (__bf16*)(ws + (size_t)2 * 1024 * 1024);       // 2 MB
    float* n1   = (float*)(ws + (size_t)4 * 1024 * 1024);        // 32 KB
    float* n2pc = (float*)(ws + (size_t)4 * 1024 * 1024 + 32768);// 32 KB
    unsigned* pmin1 = (unsigned*)(ws + (size_t)4 * 1024 * 1024 + 65536); // 1 MB
    unsigned* pmin2 = pmin1 + (size_t)NCHUNK * NB;                        // 1 MB

    conv_norm_kernel<<<2 * NB / 4, 256, 0, stream>>>(desc1, desc2, d1b, d2b, n1, n2pc);
    snn_main_kernel<<<dim3(NB / BM, NCHUNK), 256, 0, stream>>>(d1b, d2b, n2pc, pmin1, pmin2);
    snn_reduce_kernel<<<NB / 256, 256, 0, stream>>>(pmin1, pmin2, n1, out);
}